// Round 7
// baseline (284.835 us; speedup 1.0000x reference)
//
#include <hip/hip_runtime.h>

// Chamfer distance, fp32 in/out, A,B = [4][8192][3], via bf16-split MFMA.
// Embedding (HW-validated R4-R6, absmax 0.0): d^2(u,v) = rw(u).cw(v), K=15:
//  rw: s2h s2l s2ll 1 1 1 | mxh myh mzh | mxh myh mzh | mxl myl mzl | 0
//  cw: 1 1 1 s2h s2l s2ll |  xh  yh  zh |  xl  yl  zl |  xh  yh  zh | 0
// Swapped operands: streamed opposite-set points are MFMA-A (min axis ->
// lane-local D regs), resident points are MFMA-B. Per MFMA: 16->1 min3 tree
// into a scalar acc per resident frag. No LDS, no barriers. 2048 blocks
// (8/CU); resident 256 pts/block, stream split 8-way; cross-split merge via
// uint atomicMin (non-negative floats: uint order == float order).

typedef __bf16 bf16x8 __attribute__((ext_vector_type(8)));
typedef float f32x16 __attribute__((ext_vector_type(16)));
typedef unsigned short u16;

constexpr int NB = 4;
constexpr int NPTS = 8192;
constexpr int NROWS = 2 * NB * NPTS;            // 65536
constexpr int FRAGS = 8;                        // resident frags -> 256 rows/block
constexpr int ROWS_PER_BLK = FRAGS * 32;        // 256
constexpr int ROWBLKS = NPTS / ROWS_PER_BLK;    // 32
constexpr int SSPLIT = 8;                       // stream split
constexpr int SPTS = NPTS / SSPLIT;             // 1024 streamed pts/block
constexpr int TILES_PER_WAVE = SPTS / 32 / 4;   // 8

// ws: streamT(rw) 2MB @0 | resT(cw) 2MB @2MB | ws_min 256KB @4MB
constexpr size_t REST_OFF = 2u << 20;
constexpr size_t WSMIN_OFF = 4u << 20;

__device__ __forceinline__ float bsplit(float x, u16& hbits, float& hf) {
    unsigned u = __float_as_uint(x);
    unsigned r = (u + 0x7FFFu + ((u >> 16) & 1u)) & 0xFFFF0000u;  // RTNE bf16
    hbits = (u16)(r >> 16);
    hf = __uint_as_float(r);
    return x - hf;   // exact
}

__global__ __launch_bounds__(256)
void chamfer_prep_kernel(const float* __restrict__ A, const float* __restrict__ B,
                         u16* __restrict__ streamT, u16* __restrict__ resT,
                         unsigned int* __restrict__ ws_min) {
    int idx = blockIdx.x * 256 + threadIdx.x;       // 0..65535
    int pt = idx & (NPTS - 1);
    int batch = (idx >> 13) & (NB - 1);
    int set = idx >> 15;                             // 0=A, 1=B
    const float* src = (set ? B : A) + ((size_t)batch * NPTS + pt) * 3;
    float x = src[0], y = src[1], z = src[2];
    float s2 = fmaf(x, x, fmaf(y, y, z * z));
    float hf, h2;
    u16 s2h, s2l, s2ll, xh, xl, yh, yl, zh, zl, mxh, mxl, myh, myl, mzh, mzl;
    float r1 = bsplit(s2, s2h, hf);
    float r2 = bsplit(r1, s2l, h2);
    bsplit(r2, s2ll, h2);
    float t;
    t = bsplit(x, xh, hf);          bsplit(t, xl, h2);
    t = bsplit(y, yh, hf);          bsplit(t, yl, h2);
    t = bsplit(z, zh, hf);          bsplit(t, zl, h2);
    t = bsplit(-2.0f * x, mxh, hf); bsplit(t, mxl, h2);
    t = bsplit(-2.0f * y, myh, hf); bsplit(t, myl, h2);
    t = bsplit(-2.0f * z, mzh, hf); bsplit(t, mzl, h2);
    const unsigned ONE = 0x3F80u;
    #define PK(a, b) ((unsigned)(a) | ((unsigned)(b) << 16))
    uint4 rw0 = make_uint4(PK(s2h, s2l), PK(s2ll, ONE), PK(ONE, ONE), PK(mxh, myh));
    uint4 rw1 = make_uint4(PK(mzh, mxh), PK(myh, mzh), PK(mxl, myl), PK(mzl, 0));
    uint4 cw0 = make_uint4(PK(ONE, ONE), PK(ONE, s2h), PK(s2l, s2ll), PK(xh, yh));
    uint4 cw1 = make_uint4(PK(zh, xl), PK(yl, zl), PK(xh, yh), PK(zh, 0));
    #undef PK
    uint4* sp = (uint4*)(streamT + (size_t)idx * 16);
    uint4* rp = (uint4*)(resT + (size_t)idx * 16);
    sp[0] = rw0; sp[1] = rw1;
    rp[0] = cw0; rp[1] = cw1;
    ws_min[idx] = 0xFFFFFFFFu;
}

__device__ __forceinline__ float tree16(const f32x16& d) {
    float m0 = fminf(fminf(d[0],  d[1]),  d[2]);    // -> v_min3
    float m1 = fminf(fminf(d[3],  d[4]),  d[5]);
    float m2 = fminf(fminf(d[6],  d[7]),  d[8]);
    float m3 = fminf(fminf(d[9],  d[10]), d[11]);
    float m4 = fminf(fminf(d[12], d[13]), d[14]);
    float n0 = fminf(fminf(m0, m1), m2);
    float n1 = fminf(fminf(m3, m4), d[15]);
    return fminf(n0, n1);
}

__global__ __launch_bounds__(256)
void chamfer_minmfma_kernel(const u16* __restrict__ streamT,
                            const u16* __restrict__ resT,
                            unsigned int* __restrict__ ws_min) {
    int bid = blockIdx.x;
    int split  = bid & (SSPLIT - 1);  bid >>= 3;
    int rowblk = bid & (ROWBLKS - 1); bid >>= 5;
    int batch  = bid & (NB - 1);      bid >>= 2;
    int dir    = bid;

    int lane = threadIdx.x & 63;
    int wave = threadIdx.x >> 6;
    int l31 = lane & 31, lh = lane >> 5;

    // Resident B-operand: this block's 256 output points (cw vectors).
    const u16* rbase = resT + (((size_t)(dir * NB + batch) * NPTS) + rowblk * ROWS_PER_BLK) * 16;
    bf16x8 res[FRAGS];
    #pragma unroll
    for (int f = 0; f < FRAGS; ++f)
        res[f] = *(const bf16x8*)(rbase + (f * 32 + l31) * 16 + lh * 8);

    // Stream A-operand: opposite set, this block's split, wave-partitioned.
    const uint4* sp = (const uint4*)streamT
                    + (size_t)((dir ^ 1) * NB + batch) * NPTS * 2
                    + (size_t)split * SPTS * 2
                    + (size_t)wave * TILES_PER_WAVE * 64
                    + (l31 * 2 + lh);

    // All 8 stream tiles for this wave issued upfront.
    uint4 pipe[TILES_PER_WAVE];
    #pragma unroll
    for (int i = 0; i < TILES_PER_WAVE; ++i) pipe[i] = sp[i * 64];

    f32x16 zf;
    #pragma unroll
    for (int j = 0; j < 16; ++j) zf[j] = 0.0f;
    float accf[FRAGS];
    #pragma unroll
    for (int f = 0; f < FRAGS; ++f) accf[f] = 3.0e38f;

    #pragma unroll
    for (int i = 0; i < TILES_PER_WAVE; ++i) {
        bf16x8 aop = __builtin_bit_cast(bf16x8, pipe[i]);
        #pragma unroll
        for (int f = 0; f < FRAGS; ++f) {
            f32x16 d = __builtin_amdgcn_mfma_f32_32x32x16_bf16(aop, res[f], zf, 0, 0, 0);
            accf[f] = fminf(accf[f], tree16(d));
        }
    }

    // Fold lh halves (lane and lane^32 hold complementary stream rows of the
    // same resident col), then one atomicMin per resident row per wave.
    unsigned int* wout = ws_min + (size_t)(dir * NB + batch) * NPTS + rowblk * ROWS_PER_BLK;
    #pragma unroll
    for (int f = 0; f < FRAGS; ++f) {
        float v = fminf(accf[f], __shfl_xor(accf[f], 32, 64));
        v = fmaxf(v, 0.0f);
        if (lh == 0) atomicMin(&wout[f * 32 + l31], __float_as_uint(v));
    }
}

__global__ __launch_bounds__(256)
void chamfer_reduce_kernel(const unsigned int* __restrict__ ws_min,
                           float* __restrict__ out) {
    constexpr float SCALE = 1.0f / (NB * NPTS * 12.8f);
    int idx = (blockIdx.x * 256 + threadIdx.x) * 4;
    uint4 v = *(const uint4*)(ws_min + idx);
    float s = sqrtf(__uint_as_float(v.x)) + sqrtf(__uint_as_float(v.y))
            + sqrtf(__uint_as_float(v.z)) + sqrtf(__uint_as_float(v.w));
    #pragma unroll
    for (int off = 32; off >= 1; off >>= 1) s += __shfl_down(s, off, 64);
    __shared__ float redl[4];
    if ((threadIdx.x & 63) == 0) redl[threadIdx.x >> 6] = s;
    __syncthreads();
    if (threadIdx.x == 0)
        atomicAdd(out, (redl[0] + redl[1] + redl[2] + redl[3]) * SCALE);
}

extern "C" void kernel_launch(void* const* d_in, const int* in_sizes, int n_in,
                              void* d_out, int out_size, void* d_ws, size_t ws_size,
                              hipStream_t stream) {
    const float* A = (const float*)d_in[0];
    const float* B = (const float*)d_in[1];
    float* out = (float*)d_out;
    u16* streamT = (u16*)d_ws;
    u16* resT = (u16*)((char*)d_ws + REST_OFF);
    unsigned int* wsm = (unsigned int*)((char*)d_ws + WSMIN_OFF);

    hipMemsetAsync(d_out, 0, sizeof(float), stream);
    chamfer_prep_kernel<<<NROWS / 256, 256, 0, stream>>>(A, B, streamT, resT, wsm);
    chamfer_minmfma_kernel<<<2 * NB * ROWBLKS * SSPLIT, 256, 0, stream>>>(streamT, resT, wsm);
    chamfer_reduce_kernel<<<NROWS / 4 / 256, 256, 0, stream>>>(wsm, out);
}

// Round 8
// 36.819 us; speedup vs baseline: 7.7361x; 7.7361x over previous
//
#include <hip/hip_runtime.h>

// Chamfer distance, fp32 in/out, A,B = [4][8192][3], via bf16-split MFMA.
// Embedding (HW-validated R4-R7, absmax 0.0): d^2(u,v) = rw(u).cw(v), K=15:
//  rw: s2h s2l s2ll 1 1 1 | mxh myh mzh | mxh myh mzh | mxl myl mzl | 0
//  cw: 1 1 1 s2h s2l s2ll |  xh  yh  zh |  xl  yl  zl |  xh  yh  zh | 0
// Swapped operands: streamed opposite-set points are MFMA-A (min axis ->
// lane-local in D), resident points are MFMA-B. Per MFMA: 16->1 min3 tree into
// a scalar acc per resident frag. No LDS staging, no barriers.
// R8 = R6 codegen shape (FRAGS=4 + DEPTH=4 ring -> 64 VGPR, no spill) +
// R7 grid scaling (SSPLIT=4 -> 2048 blocks = 8/CU) + atomicMin cross-split
// merge. __launch_bounds__(256,4) caps VGPR at 128 as spill insurance.

typedef __bf16 bf16x8 __attribute__((ext_vector_type(8)));
typedef float f32x16 __attribute__((ext_vector_type(16)));
typedef unsigned short u16;

constexpr int NB = 4;
constexpr int NPTS = 8192;
constexpr int NROWS = 2 * NB * NPTS;            // 65536
constexpr int FRAGS = 4;                        // resident frags -> 128 rows/block
constexpr int ROWS_PER_BLK = FRAGS * 32;        // 128
constexpr int ROWBLKS = NPTS / ROWS_PER_BLK;    // 64
constexpr int SSPLIT = 4;                       // stream split
constexpr int SPTS = NPTS / SSPLIT;             // 2048 streamed pts/block
constexpr int TILES_PER_WAVE = SPTS / 32 / 4;   // 16
constexpr int DEPTH = 4;                        // prefetch ring

// ws: streamT(rw) 2MB @0 | resT(cw) 2MB @2MB | ws_min 256KB @4MB
constexpr size_t REST_OFF = 2u << 20;
constexpr size_t WSMIN_OFF = 4u << 20;

__device__ __forceinline__ float bsplit(float x, u16& hbits, float& hf) {
    unsigned u = __float_as_uint(x);
    unsigned r = (u + 0x7FFFu + ((u >> 16) & 1u)) & 0xFFFF0000u;  // RTNE bf16
    hbits = (u16)(r >> 16);
    hf = __uint_as_float(r);
    return x - hf;   // exact
}

__global__ __launch_bounds__(256)
void chamfer_prep_kernel(const float* __restrict__ A, const float* __restrict__ B,
                         u16* __restrict__ streamT, u16* __restrict__ resT,
                         unsigned int* __restrict__ ws_min) {
    int idx = blockIdx.x * 256 + threadIdx.x;       // 0..65535
    int pt = idx & (NPTS - 1);
    int batch = (idx >> 13) & (NB - 1);
    int set = idx >> 15;                             // 0=A, 1=B
    const float* src = (set ? B : A) + ((size_t)batch * NPTS + pt) * 3;
    float x = src[0], y = src[1], z = src[2];
    float s2 = fmaf(x, x, fmaf(y, y, z * z));
    float hf, h2;
    u16 s2h, s2l, s2ll, xh, xl, yh, yl, zh, zl, mxh, mxl, myh, myl, mzh, mzl;
    float r1 = bsplit(s2, s2h, hf);
    float r2 = bsplit(r1, s2l, h2);
    bsplit(r2, s2ll, h2);
    float t;
    t = bsplit(x, xh, hf);          bsplit(t, xl, h2);
    t = bsplit(y, yh, hf);          bsplit(t, yl, h2);
    t = bsplit(z, zh, hf);          bsplit(t, zl, h2);
    t = bsplit(-2.0f * x, mxh, hf); bsplit(t, mxl, h2);
    t = bsplit(-2.0f * y, myh, hf); bsplit(t, myl, h2);
    t = bsplit(-2.0f * z, mzh, hf); bsplit(t, mzl, h2);
    const unsigned ONE = 0x3F80u;
    #define PK(a, b) ((unsigned)(a) | ((unsigned)(b) << 16))
    uint4 rw0 = make_uint4(PK(s2h, s2l), PK(s2ll, ONE), PK(ONE, ONE), PK(mxh, myh));
    uint4 rw1 = make_uint4(PK(mzh, mxh), PK(myh, mzh), PK(mxl, myl), PK(mzl, 0));
    uint4 cw0 = make_uint4(PK(ONE, ONE), PK(ONE, s2h), PK(s2l, s2ll), PK(xh, yh));
    uint4 cw1 = make_uint4(PK(zh, xl), PK(yl, zl), PK(xh, yh), PK(zh, 0));
    #undef PK
    uint4* sp = (uint4*)(streamT + (size_t)idx * 16);
    uint4* rp = (uint4*)(resT + (size_t)idx * 16);
    sp[0] = rw0; sp[1] = rw1;
    rp[0] = cw0; rp[1] = cw1;
    ws_min[idx] = 0xFFFFFFFFu;
}

__device__ __forceinline__ float tree16(const f32x16& d) {
    float m0 = fminf(fminf(d[0],  d[1]),  d[2]);    // -> v_min3
    float m1 = fminf(fminf(d[3],  d[4]),  d[5]);
    float m2 = fminf(fminf(d[6],  d[7]),  d[8]);
    float m3 = fminf(fminf(d[9],  d[10]), d[11]);
    float m4 = fminf(fminf(d[12], d[13]), d[14]);
    float n0 = fminf(fminf(m0, m1), m2);
    float n1 = fminf(fminf(m3, m4), d[15]);
    return fminf(n0, n1);
}

__global__ __launch_bounds__(256, 4)
void chamfer_minmfma_kernel(const u16* __restrict__ streamT,
                            const u16* __restrict__ resT,
                            unsigned int* __restrict__ ws_min) {
    int bid = blockIdx.x;
    int split  = bid & (SSPLIT - 1);  bid >>= 2;
    int rowblk = bid & (ROWBLKS - 1); bid >>= 6;
    int batch  = bid & (NB - 1);      bid >>= 2;
    int dir    = bid;

    int lane = threadIdx.x & 63;
    int wave = threadIdx.x >> 6;
    int l31 = lane & 31, lh = lane >> 5;

    // Resident B-operand: this block's 128 output points (cw vectors).
    const u16* rbase = resT + (((size_t)(dir * NB + batch) * NPTS) + rowblk * ROWS_PER_BLK) * 16;
    bf16x8 res[FRAGS];
    #pragma unroll
    for (int f = 0; f < FRAGS; ++f)
        res[f] = *(const bf16x8*)(rbase + (f * 32 + l31) * 16 + lh * 8);

    // Stream A-operand: opposite set, this block's split, wave-partitioned.
    const uint4* wp = (const uint4*)streamT
                    + (size_t)((dir ^ 1) * NB + batch) * NPTS * 2
                    + (size_t)split * SPTS * 2
                    + (size_t)wave * TILES_PER_WAVE * 64
                    + (l31 * 2 + lh);

    f32x16 zf;
    #pragma unroll
    for (int j = 0; j < 16; ++j) zf[j] = 0.0f;
    float accf[FRAGS];
    #pragma unroll
    for (int f = 0; f < FRAGS; ++f) accf[f] = 3.0e38f;

    uint4 pipe[DEPTH];
    #pragma unroll
    for (int i = 0; i < DEPTH; ++i) pipe[i] = wp[i * 64];

    for (int t = 0; t < TILES_PER_WAVE; t += DEPTH) {
        #pragma unroll
        for (int u = 0; u < DEPTH; ++u) {
            uint4 cur = pipe[u];
            // Tail prefetch overreads into resT region: valid memory, never used.
            pipe[u] = wp[(t + u + DEPTH) * 64];
            bf16x8 aop = __builtin_bit_cast(bf16x8, cur);
            #pragma unroll
            for (int f = 0; f < FRAGS; ++f) {
                f32x16 d = __builtin_amdgcn_mfma_f32_32x32x16_bf16(aop, res[f], zf, 0, 0, 0);
                accf[f] = fminf(accf[f], tree16(d));
            }
        }
    }

    // Fold lh halves (lane and lane^32 hold complementary stream rows of the
    // same resident col), then one atomicMin per resident row per wave.
    unsigned int* wout = ws_min + (size_t)(dir * NB + batch) * NPTS + rowblk * ROWS_PER_BLK;
    #pragma unroll
    for (int f = 0; f < FRAGS; ++f) {
        float v = fminf(accf[f], __shfl_xor(accf[f], 32, 64));
        v = fmaxf(v, 0.0f);   // >= 0: uint order == float order
        if (lh == 0) atomicMin(&wout[f * 32 + l31], __float_as_uint(v));
    }
}

__global__ __launch_bounds__(256)
void chamfer_reduce_kernel(const unsigned int* __restrict__ ws_min,
                           float* __restrict__ out) {
    constexpr float SCALE = 1.0f / (NB * NPTS * 12.8f);
    int idx = (blockIdx.x * 256 + threadIdx.x) * 4;
    uint4 v = *(const uint4*)(ws_min + idx);
    float s = sqrtf(__uint_as_float(v.x)) + sqrtf(__uint_as_float(v.y))
            + sqrtf(__uint_as_float(v.z)) + sqrtf(__uint_as_float(v.w));
    #pragma unroll
    for (int off = 32; off >= 1; off >>= 1) s += __shfl_down(s, off, 64);
    __shared__ float redl[4];
    if ((threadIdx.x & 63) == 0) redl[threadIdx.x >> 6] = s;
    __syncthreads();
    if (threadIdx.x == 0)
        atomicAdd(out, (redl[0] + redl[1] + redl[2] + redl[3]) * SCALE);
}

extern "C" void kernel_launch(void* const* d_in, const int* in_sizes, int n_in,
                              void* d_out, int out_size, void* d_ws, size_t ws_size,
                              hipStream_t stream) {
    const float* A = (const float*)d_in[0];
    const float* B = (const float*)d_in[1];
    float* out = (float*)d_out;
    u16* streamT = (u16*)d_ws;
    u16* resT = (u16*)((char*)d_ws + REST_OFF);
    unsigned int* wsm = (unsigned int*)((char*)d_ws + WSMIN_OFF);

    hipMemsetAsync(d_out, 0, sizeof(float), stream);
    chamfer_prep_kernel<<<NROWS / 256, 256, 0, stream>>>(A, B, streamT, resT, wsm);
    chamfer_minmfma_kernel<<<2 * NB * ROWBLKS * SSPLIT, 256, 0, stream>>>(streamT, resT, wsm);
    chamfer_reduce_kernel<<<NROWS / 4 / 256, 256, 0, stream>>>(wsm, out);
}